// Round 11
// baseline (19.563 us; speedup 1.0000x reference)
//
#include <hip/hip_runtime.h>

// Shapes (compile-time constants from the reference)
#define BQ 4     // B
#define VV 384   // V visible nodes
#define HH 128   // H hidden nodes
#define NN 512   // N = V + H
#define HDIM 64  // HD
#define TD 128   // T*D

// Wave-uniform broadcast: readlane (VALU->SGPR, ~4cyc) instead of __shfl
// (ds_bpermute, ~60+cyc LDS-crossbar latency). Index must be wave-uniform.
__device__ __forceinline__ float BCAST(float v, int l) {
    return __int_as_float(__builtin_amdgcn_readlane(__float_as_int(v), l));
}

// K1: visible rows only. One row per 128-thread block (2 waves).
// Layer in1 (K=128) is split across the 2 waves -> ONE cheap 2-wave barrier;
// layers in2/e1/e2 (K=64) run redundantly in-register in both waves (no sync).
// 1536 blocks x 2 waves = 3072 waves = 12/CU (R9 occupancy, 1/4 the barriers).
__global__ __launch_bounds__(128) void k_rowpipe(
    const float* __restrict__ x,       // (B*V,128)
    const float* __restrict__ w_in1,   // (128,64)
    const float* __restrict__ b_in1,   // (64)
    const float* __restrict__ w_in2,   // (64,64)
    const float* __restrict__ b_in2,   // (64)
    const float* __restrict__ w_e1,    // (128,64) ; rows [64:128) = sender half
    const float* __restrict__ b_e1,    // (64)
    const float* __restrict__ w_e2,    // (64,64)
    const float* __restrict__ b_e2,    // (64)
    float* __restrict__ E2)            // (B*V,64) in workspace
{
    __shared__ float part[2][HDIM];

    const int hf   = threadIdx.x >> 6;    // 0..1 : K-half of in1
    const int lane = threadIdx.x & 63;
    const int row  = blockIdx.x;          // 0 .. B*V-1

    const float* xr = x + (size_t)row * TD;
    const float xv = xr[64 * hf + lane];  // my half of the x row

    // layer in1: K=128 split across the 2 waves (kg in [64*hf, 64*hf+64))
    float a0 = 0.f, a1 = 0.f;
    #pragma unroll 8
    for (int k = 0; k < 64; k += 2) {
        const int kg = 64 * hf + k;
        a0 = fmaf(BCAST(xv, k),     w_in1[kg * HDIM + lane],       a0);
        a1 = fmaf(BCAST(xv, k + 1), w_in1[(kg + 1) * HDIM + lane], a1);
    }
    part[hf][lane] = a0 + a1;
    __syncthreads();
    const float h1 = fmaxf(part[0][lane] + part[1][lane] + b_in1[lane], 0.f);

    // layer in2: K=64, redundant in both waves (no barrier)
    a0 = b_in2[lane]; a1 = 0.f;
    #pragma unroll 8
    for (int k = 0; k < HDIM; k += 2) {
        a0 = fmaf(BCAST(h1, k),     w_in2[k * HDIM + lane],       a0);
        a1 = fmaf(BCAST(h1, k + 1), w_in2[(k + 1) * HDIM + lane], a1);
    }
    const float h2 = fmaxf(a0 + a1, 0.f);

    // sender-side edge contribution: bb = h2 @ w_e1[HD:]
    a0 = 0.f; a1 = 0.f;
    #pragma unroll 8
    for (int k = 0; k < HDIM; k += 2) {
        a0 = fmaf(BCAST(h2, k),     w_e1[(HDIM + k) * HDIM + lane],     a0);
        a1 = fmaf(BCAST(h2, k + 1), w_e1[(HDIM + k + 1) * HDIM + lane], a1);
    }
    const float e1 = fmaxf(a0 + a1 + b_e1[lane], 0.f);

    // edge layer 2
    a0 = b_e2[lane]; a1 = 0.f;
    #pragma unroll 8
    for (int k = 0; k < HDIM; k += 2) {
        a0 = fmaf(BCAST(e1, k),     w_e2[k * HDIM + lane],       a0);
        a1 = fmaf(BCAST(e1, k + 1), w_e2[(k + 1) * HDIM + lane], a1);
    }
    if (hf == 0)
        E2[(size_t)row * HDIM + lane] = fmaxf(a0 + a1, 0.f);
}

// K2: byte-identical to R9 (proven 18.3 µs config).
// 256 blocks x 1024 threads (16 waves), 2 hidden rows per block.
__global__ __launch_bounds__(1024) void k_agg_out(
    const float* __restrict__ adj,   // (B,N,N)
    const float* __restrict__ E2,    // (B*V,64)
    const float* __restrict__ b_e1, const float* __restrict__ w_e2,
    const float* __restrict__ b_e2,
    const float* __restrict__ w_n1, const float* __restrict__ b_n1,
    const float* __restrict__ w_n2, const float* __restrict__ b_n2,
    const float* __restrict__ w_out, // (64,128)
    const float* __restrict__ b_out, // (128)
    float* __restrict__ out)         // (B,H,128)
{
    const int blk  = blockIdx.x;          // 0..255
    const int b    = blk >> 6;
    const int pair = blk & 63;
    const int wid  = threadIdx.x >> 6;    // 0..15
    const int lane = threadIdx.x & 63;

    const int i0 = VV + pair * 2;
    const float* adjr0 = adj + ((size_t)b * NN + i0) * NN;
    const float* adjr1 = adjr0 + NN;
    const int j0 = wid * 32;              // waves 0-11 visible, 12-15 hidden

    const float adjv = (lane < 32) ? adjr0[j0 + lane] : adjr1[j0 + lane - 32];

    __shared__ float redA[12][2][HDIM];
    __shared__ float hs[4][2];
    __shared__ float e2c[HDIM];

    if (wid < 12) {
        const float* e2b = E2 + ((size_t)b * VV + j0) * HDIM;
        float p0 = 0.f, p1 = 0.f, q0 = 0.f, q1 = 0.f;
        #pragma unroll 8
        for (int jj = 0; jj < 32; jj += 2) {
            const float e0 = e2b[jj * HDIM + lane];
            const float e1 = e2b[(jj + 1) * HDIM + lane];
            p0 = fmaf(BCAST(adjv, jj),      e0, p0);
            q0 = fmaf(BCAST(adjv, 32 + jj), e0, q0);
            p1 = fmaf(BCAST(adjv, jj + 1),  e1, p1);
            q1 = fmaf(BCAST(adjv, 33 + jj), e1, q1);
        }
        redA[wid][0][lane] = p0 + p1;
        redA[wid][1][lane] = q0 + q1;
    } else {
        float s = adjv;
        s += __shfl_xor(s, 1, 64);
        s += __shfl_xor(s, 2, 64);
        s += __shfl_xor(s, 4, 64);
        s += __shfl_xor(s, 8, 64);
        s += __shfl_xor(s, 16, 64);
        if (lane == 0)  hs[wid - 12][0] = s;
        if (lane == 32) hs[wid - 12][1] = s;
        if (wid == 12) {
            const float e1c = fmaxf(b_e1[lane], 0.f);
            float t0 = b_e2[lane], t1 = 0.f;
            #pragma unroll 8
            for (int k = 0; k < HDIM; k += 2) {
                t0 = fmaf(BCAST(e1c, k),     w_e2[k * HDIM + lane],       t0);
                t1 = fmaf(BCAST(e1c, k + 1), w_e2[(k + 1) * HDIM + lane], t1);
            }
            e2c[lane] = fmaxf(t0 + t1, 0.f);
        }
    }
    __syncthreads();

    const int g  = wid >> 3;   // row group (0/1)
    const int w8 = wid & 7;

    const float hsum = hs[0][g] + hs[1][g] + hs[2][g] + hs[3][g];
    float agg = hsum * e2c[lane];
    #pragma unroll
    for (int w = 0; w < 12; ++w) agg += redA[w][g][lane];

    // layer n1: K split 8 ways across the group's waves
    __shared__ float redB[16][HDIM];
    {
        float t0 = 0.f, t1 = 0.f;
        #pragma unroll
        for (int t = 0; t < 8; t += 2) {
            const int k = 8 * w8 + t;
            t0 = fmaf(BCAST(agg, k),     w_n1[k * HDIM + lane],       t0);
            t1 = fmaf(BCAST(agg, k + 1), w_n1[(k + 1) * HDIM + lane], t1);
        }
        redB[wid][lane] = t0 + t1;
    }
    __syncthreads();
    float n1 = b_n1[lane];
    #pragma unroll
    for (int w = 0; w < 8; ++w) n1 += redB[g * 8 + w][lane];
    n1 = fmaxf(n1, 0.f);

    // layer n2
    __shared__ float redC[16][HDIM];
    {
        float t0 = 0.f, t1 = 0.f;
        #pragma unroll
        for (int t = 0; t < 8; t += 2) {
            const int k = 8 * w8 + t;
            t0 = fmaf(BCAST(n1, k),     w_n2[k * HDIM + lane],       t0);
            t1 = fmaf(BCAST(n1, k + 1), w_n2[(k + 1) * HDIM + lane], t1);
        }
        redC[wid][lane] = t0 + t1;
    }
    __syncthreads();
    float n2 = b_n2[lane];
    #pragma unroll
    for (int w = 0; w < 8; ++w) n2 += redC[g * 8 + w][lane];
    n2 = fmaxf(n2, 0.f);

    // out layer: 128 outputs, K split 8 ways
    __shared__ float redD[16][TD];
    {
        float o0 = 0.f, o1 = 0.f;
        #pragma unroll
        for (int t = 0; t < 8; ++t) {
            const int k = 8 * w8 + t;
            const float v = BCAST(n2, k);
            o0 = fmaf(v, w_out[k * TD + lane],      o0);
            o1 = fmaf(v, w_out[k * TD + 64 + lane], o1);
        }
        redD[wid][lane]      = o0;
        redD[wid][64 + lane] = o1;
    }
    __syncthreads();

    if (w8 < 2) {
        const int col = w8 * 64 + lane;
        float o = b_out[col];
        #pragma unroll
        for (int w = 0; w < 8; ++w) o += redD[g * 8 + w][col];
        const int orow = b * HH + pair * 2 + g;
        out[(size_t)orow * TD + col] = o;
    }
}

extern "C" void kernel_launch(void* const* d_in, const int* in_sizes, int n_in,
                              void* d_out, int out_size, void* d_ws, size_t ws_size,
                              hipStream_t stream) {
    const float* x     = (const float*)d_in[0];
    const float* adj   = (const float*)d_in[1];
    const float* w_in1 = (const float*)d_in[2];
    const float* b_in1 = (const float*)d_in[3];
    const float* w_in2 = (const float*)d_in[4];
    const float* b_in2 = (const float*)d_in[5];
    const float* w_e1  = (const float*)d_in[6];
    const float* b_e1  = (const float*)d_in[7];
    const float* w_e2  = (const float*)d_in[8];
    const float* b_e2  = (const float*)d_in[9];
    const float* w_n1  = (const float*)d_in[10];
    const float* b_n1  = (const float*)d_in[11];
    const float* w_n2  = (const float*)d_in[12];
    const float* b_n2  = (const float*)d_in[13];
    const float* w_out = (const float*)d_in[14];
    const float* b_out = (const float*)d_in[15];
    float* out = (float*)d_out;
    float* E2  = (float*)d_ws;   // B*V*64 floats = 384 KiB

    // K1: one row per 128-thread block -> 1536 blocks (3072 waves, 12/CU)
    k_rowpipe<<<BQ * VV, 128, 0, stream>>>(
        x, w_in1, b_in1, w_in2, b_in2, w_e1, b_e1, w_e2, b_e2, E2);
    // K2: 256 blocks x 1024 threads, 2 hidden rows per block
    k_agg_out<<<BQ * HH / 2, 1024, 0, stream>>>(
        adj, E2, b_e1, w_e2, b_e2, w_n1, b_n1, w_n2, b_n2, w_out, b_out, out);
}